// Round 21
// baseline (257.179 us; speedup 1.0000x reference)
//
#include <hip/hip_runtime.h>

// ---------------------------------------------------------------------------
// Problem constants (fixed by setup_inputs)
// ---------------------------------------------------------------------------
#define N_OP   50000
#define N_M    5000
#define N_A    2000
#define C_OP   256
#define C_M    128
#define C_A    128
#define E_OO   200000
#define E_OM   200000
#define E_MA   60000
#define E_DIM  8

#define OUT_OP_OFF 0
#define OUT_M_OFF  (N_OP * C_OP)
#define OUT_A_OFF  (N_OP * C_OP + N_M * C_M)

typedef short bf16x8 __attribute__((ext_vector_type(8)));
typedef float f32x4 __attribute__((ext_vector_type(4)));
typedef __attribute__((address_space(1))) const unsigned gu32;
typedef __attribute__((address_space(3))) unsigned lu32;

__device__ __forceinline__ unsigned short f2bf(float f) {
    unsigned u = __float_as_uint(f);
    unsigned r = (u + 0x7FFFu + ((u >> 16) & 1u)) >> 16;
    return (unsigned short)r;
}
__device__ __forceinline__ float bf2f(unsigned short h) {
    return __uint_as_float(((unsigned)h) << 16);
}

// ---------------------------------------------------------------------------
// Fused prep: hist+rank / convert (op) / init+convert (m,a) / weight-pack
// (verified rounds 19-20).
// ---------------------------------------------------------------------------
#define NTOT 107000
#define ETOT 660000

#define I3_OP (N_OP * C_OP / 4)
#define I3_M  (I3_OP + N_M * C_M / 4)
#define I3_A  (I3_M + N_A * C_A / 4)

#define PK_P   131072
#define PK_S   262144
#define PK_OL  294912
#define PK_OR  311296
#define PK_ML  327680
#define PK_MR  344064
#define PK_BP  344576
#define PK_BS  345088

#define PREP_HIST_BLK 645                       // ceil(660000 / 1024)
#define PREP_INIT_BLK (I3_A / 256)              // 13375
#define PREP_PACK_BLK (PK_BS / 256)             // 1348
#define PREP_FRONT    (6 * PREP_HIST_BLK)       // 3870
#define PREP_TOTAL    (PREP_HIST_BLK + PREP_INIT_BLK + PREP_PACK_BLK)

__device__ __forceinline__ void init_one(const float* __restrict__ x,
                                         const float* __restrict__ b1,
                                         float* __restrict__ out,
                                         unsigned short* __restrict__ xc,
                                         int i, int cmask) {
    float4 v = ((const float4*)x)[i];
    const int cb = i & cmask;
    float4 b = ((const float4*)b1)[cb];
    float4 o;
    o.x = v.x + b.x; o.y = v.y + b.y; o.z = v.z + b.z; o.w = v.w + b.w;
    ((float4*)out)[i] = o;
    ushort4 r;
    r.x = f2bf(v.x); r.y = f2bf(v.y); r.z = f2bf(v.z); r.w = f2bf(v.w);
    ((ushort4*)xc)[i] = r;
}

__device__ __forceinline__ void hist_one(
    int i,
    const int* __restrict__ dP, const int* __restrict__ dS,
    const int* __restrict__ dO, const int* __restrict__ dA,
    int* __restrict__ cP, int* __restrict__ cS,
    int* __restrict__ cO, int* __restrict__ cA, int* __restrict__ rk) {
    if (i < 200000)      rk[i] = atomicAdd(&cP[dP[i]], 1);
    else if (i < 400000) rk[i] = atomicAdd(&cS[dS[i - 200000]], 1);
    else if (i < 600000) rk[i] = atomicAdd(&cO[dO[i - 400000]], 1);
    else if (i < ETOT)   rk[i] = atomicAdd(&cA[dA[i - 600000]], 1);
}

__global__ void prep_all(
    const int* __restrict__ dP, const int* __restrict__ dS,
    const int* __restrict__ dO, const int* __restrict__ dA,
    int* __restrict__ cP, int* __restrict__ cS,
    int* __restrict__ cO, int* __restrict__ cA, int* __restrict__ rk,
    const float* __restrict__ x_op, const float* __restrict__ x_m,
    const float* __restrict__ x_a,
    const float* __restrict__ bO, const float* __restrict__ bA,
    float* __restrict__ out_m, float* __restrict__ out_a,
    unsigned short* __restrict__ xcop, unsigned short* __restrict__ xcm,
    unsigned short* __restrict__ xca,
    const float* __restrict__ WlP, const float* __restrict__ WrP,
    const float* __restrict__ WlS, const float* __restrict__ WrS,
    const float* __restrict__ WOl, const float* __restrict__ WOr,
    const float* __restrict__ WMl, const float* __restrict__ WMr,
    const float* __restrict__ blP, const float* __restrict__ brP,
    const float* __restrict__ blS, const float* __restrict__ brS,
    unsigned short* __restrict__ BtP, unsigned short* __restrict__ BtS,
    unsigned short* __restrict__ BtOL, unsigned short* __restrict__ BtOR,
    unsigned short* __restrict__ BtML, unsigned short* __restrict__ BtMR,
    float* __restrict__ biasP, float* __restrict__ biasS) {
    const int b = blockIdx.x;
    const int tid = threadIdx.x;
    int ib;
    if (b < PREP_FRONT) {
        if ((b % 6) == 5) {              // hist role: 4 edges per thread
            const int h = b / 6;
            const int base = h * 1024 + tid;
            hist_one(base,       dP, dS, dO, dA, cP, cS, cO, cA, rk);
            hist_one(base + 256, dP, dS, dO, dA, cP, cS, cO, cA, rk);
            hist_one(base + 512, dP, dS, dO, dA, cP, cS, cO, cA, rk);
            hist_one(base + 768, dP, dS, dO, dA, cP, cS, cO, cA, rk);
            return;
        }
        ib = b - b / 6;
    } else {
        ib = b - PREP_HIST_BLK;
    }
    if (ib < PREP_INIT_BLK) {
        int i = ib * 256 + tid;
        if (i < I3_OP) {
            float4 v = ((const float4*)x_op)[i];
            ushort4 r;
            r.x = f2bf(v.x); r.y = f2bf(v.y); r.z = f2bf(v.z); r.w = f2bf(v.w);
            ((ushort4*)xcop)[i] = r;
        } else if (i < I3_M) {
            init_one(x_m, bO, out_m, xcm, i - I3_OP, 31);
        } else {
            init_one(x_a, bA, out_a, xca, i - I3_M, 31);
        }
    } else {
        int i = (ib - PREP_INIT_BLK) * 256 + tid;
        if (i < PK_P) {
            int n = i >> 8, k = i & 255;
            BtP[i] = f2bf((n < 256) ? WlP[k * 256 + n] : WrP[k * 256 + (n - 256)]);
        } else if (i < PK_S) {
            int j = i - PK_P; int n = j >> 8, k = j & 255;
            BtS[j] = f2bf((n < 256) ? WlS[k * 256 + n] : WrS[k * 256 + (n - 256)]);
        } else if (i < PK_OL) {
            int j = i - PK_S; int n = j >> 8, k = j & 255;
            BtOL[j] = f2bf(WOl[k * 128 + n]);
        } else if (i < PK_OR) {
            int j = i - PK_OL; int n = j >> 7, k = j & 127;
            BtOR[j] = f2bf(WOr[k * 128 + n]);
        } else if (i < PK_ML) {
            int j = i - PK_OR; int n = j >> 7, k = j & 127;
            BtML[j] = f2bf(WMl[k * 128 + n]);
        } else if (i < PK_MR) {
            int j = i - PK_ML; int n = j >> 7, k = j & 127;
            BtMR[j] = f2bf(WMr[k * 128 + n]);
        } else if (i < PK_BP) {
            int j = i - PK_MR;
            biasP[j] = (j < 256) ? blP[j] : brP[j - 256];
        } else if (i < PK_BS) {
            int j = i - PK_BP;
            biasS[j] = (j < 256) ? blS[j] : brS[j - 256];
        }
    }
}

// ---------------------------------------------------------------------------
// MFMA bf16 GEMM body: m97 structure — 128x128 tile, BK=64, single-buffered
// 32KB LDS, XOR-swizzled (verified rounds 15-20).
// ---------------------------------------------------------------------------
__device__ __forceinline__ void gload_lds16(const void* g, void* l) {
    __builtin_amdgcn_global_load_lds((gu32*)g, (lu32*)l, 16, 0, 0);
}

__device__ __forceinline__ void gemm_body(
    const unsigned short* __restrict__ A, const unsigned short* __restrict__ Bt,
    const float* __restrict__ bias, unsigned short* __restrict__ C,
    int M, int K, int ldc, int bx, int by,
    unsigned short (&As)[128 * 64], unsigned short (&Bs)[128 * 64]) {
    const int tid  = threadIdx.x;
    const int lane = tid & 63;
    const int wid  = tid >> 6;
    const int m0   = bx * 128;
    const int n0   = by * 128;

    f32x4 acc[4][4] = {};

    const int srow   = tid >> 3;
    const int scolb  = (tid & 7) * 16;
    const int scole  = (scolb ^ ((srow & 7) << 4)) >> 1;

    int grA[4], grB[4];
#pragma unroll
    for (int i = 0; i < 4; ++i) {
        int gr = m0 + i * 32 + srow;
        grA[i] = (gr < M) ? gr : M - 1;
        grB[i] = n0 + i * 32 + srow;
    }

    const int nt = K >> 6;
    const int wr = (wid >> 1) * 64;
    const int wc = (wid & 1) * 64;

    for (int t = 0; t < nt; ++t) {
#pragma unroll
        for (int i = 0; i < 4; ++i)
            gload_lds16(A + (size_t)grA[i] * K + t * 64 + scole, &As[i * 2048 + tid * 8]);
#pragma unroll
        for (int i = 0; i < 4; ++i)
            gload_lds16(Bt + (size_t)grB[i] * K + t * 64 + scole, &Bs[i * 2048 + tid * 8]);
        asm volatile("s_waitcnt vmcnt(0)" ::: "memory");
        __syncthreads();
#pragma unroll
        for (int kh = 0; kh < 2; ++kh) {
            const int kob = kh * 64 + (lane >> 4) * 16;
            bf16x8 a[4], b[4];
#pragma unroll
            for (int mi = 0; mi < 4; ++mi) {
                const int row = wr + mi * 16 + (lane & 15);
                a[mi] = *(const bf16x8*)((const char*)As + row * 128 +
                                         (kob ^ ((row & 7) << 4)));
            }
#pragma unroll
            for (int ni = 0; ni < 4; ++ni) {
                const int row = wc + ni * 16 + (lane & 15);
                b[ni] = *(const bf16x8*)((const char*)Bs + row * 128 +
                                         (kob ^ ((row & 7) << 4)));
            }
#pragma unroll
            for (int mi = 0; mi < 4; ++mi)
#pragma unroll
                for (int ni = 0; ni < 4; ++ni)
                    acc[mi][ni] = __builtin_amdgcn_mfma_f32_16x16x32_bf16(
                        a[mi], b[ni], acc[mi][ni], 0, 0, 0);
        }
        __syncthreads();
    }

    const int crow = (lane >> 4) * 4;
    const int ccol = lane & 15;
    float bcol[4];
#pragma unroll
    for (int ni = 0; ni < 4; ++ni) bcol[ni] = bias[n0 + wc + ni * 16 + ccol];
#pragma unroll
    for (int mi = 0; mi < 4; ++mi) {
#pragma unroll
        for (int j = 0; j < 4; ++j) {
            const int row = m0 + wr + mi * 16 + crow + j;
            if (row < M) {
                unsigned short* pc = C + (size_t)row * ldc + n0 + wc + ccol;
#pragma unroll
                for (int ni = 0; ni < 4; ++ni)
                    pc[ni * 16] = f2bf(acc[mi][ni][j] + bcol[ni]);
            }
        }
    }
}

// succ GEMM with bijective XCD-chunk swizzle (verified rounds 17-20)
__global__ __launch_bounds__(256) void mfma_gemm(
    const unsigned short* __restrict__ A, const unsigned short* __restrict__ Bt,
    const float* __restrict__ bias, unsigned short* __restrict__ C,
    int M, int K, int ldc) {
    __shared__ unsigned short As[128 * 64];
    __shared__ unsigned short Bs[128 * 64];
    const int b = blockIdx.x;
    const int xcd = b & 7, pos = b >> 3;
    const int lb = ((xcd < 4) ? xcd * 196 : 4 * 196 + (xcd - 4) * 195) + pos;
    gemm_body(A, Bt, bias, C, M, K, ldc, lb >> 2, lb & 3, As, Bs);
}

// ---------------------------------------------------------------------------
// gemm_multi: conv-1 GEMM + o2m-L 5-per-A-tile XCD-clustered + 3 tiny GEMMs
// + atomic-free CSR scatter (verified rounds 17-20).
// ---------------------------------------------------------------------------
#define MT_OPB 391
#define MT_MB  40
#define MT_AB  16
#define GM_SWZ   1955
#define GM_SMALL 2051
#define GM_TOTAL 4630

__global__ __launch_bounds__(256) void gemm_multi(
    const unsigned short* __restrict__ xc_op, const unsigned short* __restrict__ xc_m,
    const unsigned short* __restrict__ xc_a,
    const unsigned short* __restrict__ BtP, const float* __restrict__ biasP,
    unsigned short* __restrict__ H,
    const unsigned short* __restrict__ BtOL, const unsigned short* __restrict__ BtOR,
    const unsigned short* __restrict__ BtML, const unsigned short* __restrict__ BtMR,
    const float* __restrict__ blO, const float* __restrict__ brO,
    const float* __restrict__ blM, const float* __restrict__ brM,
    unsigned short* __restrict__ xlbO, unsigned short* __restrict__ xrbO,
    unsigned short* __restrict__ xlbM, unsigned short* __restrict__ xrbM,
    const int* __restrict__ sP, const int* __restrict__ dP,
    const int* __restrict__ sS, const int* __restrict__ dS,
    const int* __restrict__ sO, const int* __restrict__ dO,
    const int* __restrict__ sA, const int* __restrict__ dA,
    const int* __restrict__ pP, const int* __restrict__ pS,
    const int* __restrict__ pO, const int* __restrict__ pA,
    const int* __restrict__ rk,
    int* __restrict__ srP, int* __restrict__ srS,
    int* __restrict__ srO, int* __restrict__ srA, int* __restrict__ eiA) {
    __shared__ unsigned short As[128 * 64];
    __shared__ unsigned short Bs[128 * 64];
    const int b = blockIdx.x;
    if (b < GM_SWZ) {
        const int xcd = b & 7, pos = b >> 3;
        const int lb = ((xcd < 3) ? xcd * 245 : 3 * 245 + (xcd - 3) * 244) + pos;
        const int bx = lb / 5, role = lb - bx * 5;
        if (role < 4)
            gemm_body(xc_op, BtP, biasP, H, N_OP, 256, 512, bx, role, As, Bs);
        else
            gemm_body(xc_op, BtOL, blO, xlbO, N_OP, 256, 128, bx, 0, As, Bs);
    } else if (b < GM_SMALL) {
        const int idx = b - GM_SWZ;
        if (idx < MT_MB)
            gemm_body(xc_m, BtOR, brO, xrbO, N_M, 128, 128, idx, 0, As, Bs);
        else if (idx < 2 * MT_MB)
            gemm_body(xc_m, BtML, blM, xlbM, N_M, 128, 128, idx - MT_MB, 0, As, Bs);
        else
            gemm_body(xc_a, BtMR, brM, xrbM, N_A, 128, 128, idx - 2 * MT_MB, 0, As, Bs);
    } else {
        const int i = (b - GM_SMALL) * 256 + (int)threadIdx.x;
        if (i < 200000) {
            srP[pP[dP[i]] + rk[i]] = sP[i];
        } else if (i < 400000) {
            const int j = i - 200000;
            srS[pS[dS[j]] + rk[i]] = sS[j];
        } else if (i < 600000) {
            const int j = i - 400000;
            srO[pO[dO[j]] + rk[i]] = sO[j];
        } else if (i < ETOT) {
            const int j = i - 600000;
            const int pos = pA[dA[j]] + rk[i];
            srA[pos] = sA[j];
            eiA[pos] = j;
        }
    }
}

// ---------------------------------------------------------------------------
// CSR scan chain (verified r4-20)
// ---------------------------------------------------------------------------
#define NB_P 49
#define NB_S 49
#define NB_O 5
#define NB_A 2

__global__ void scan_blk4(const int* __restrict__ cP, const int* __restrict__ cS,
                          const int* __restrict__ cO, const int* __restrict__ cA,
                          int* __restrict__ pP, int* __restrict__ pS,
                          int* __restrict__ pO, int* __restrict__ pA,
                          int* __restrict__ bsum) {
    __shared__ int smem[1024];
    int b = blockIdx.x;
    const int* cnt; int* ptr; int n; int bo;
    if (b < NB_P)                { cnt = cP; ptr = pP; n = 50000; bo = 0; }
    else if (b < NB_P + NB_S)    { cnt = cS; ptr = pS; n = 50000; bo = 64;  b -= NB_P; }
    else if (b < NB_P + NB_S + NB_O) { cnt = cO; ptr = pO; n = 5000; bo = 128; b -= NB_P + NB_S; }
    else                         { cnt = cA; ptr = pA; n = 2000; bo = 192; b -= NB_P + NB_S + NB_O; }
    const int tid = threadIdx.x;
    const int i = b * 1024 + tid;
    const int v = (i < n) ? cnt[i] : 0;
    smem[tid] = v;
    __syncthreads();
    for (int o = 1; o < 1024; o <<= 1) {
        int t = (tid >= o) ? smem[tid - o] : 0;
        __syncthreads();
        smem[tid] += t;
        __syncthreads();
    }
    if (i < n) ptr[i] = smem[tid] - v;
    if (tid == 1023) bsum[bo + b] = smem[1023];
}

__global__ void scan_tops4(const int* __restrict__ bsum, int* __restrict__ boff,
                           int* __restrict__ pP, int* __restrict__ pS,
                           int* __restrict__ pO, int* __restrict__ pA) {
    __shared__ int smem[1024];
    const int seg = blockIdx.x;
    const int nb = (seg < 2) ? 49 : (seg == 2 ? 5 : 2);
    const int off = seg * 64;
    int* ptr_n = (seg == 0) ? pP + 50000 : (seg == 1) ? pS + 50000
               : (seg == 2) ? pO + 5000 : pA + 2000;
    const int tid = threadIdx.x;
    const int v = (tid < nb) ? bsum[off + tid] : 0;
    smem[tid] = v;
    __syncthreads();
    for (int o = 1; o < 1024; o <<= 1) {
        int t = (tid >= o) ? smem[tid - o] : 0;
        __syncthreads();
        smem[tid] += t;
        __syncthreads();
    }
    if (tid < nb) boff[off + tid] = smem[tid] - v;
    if (tid == 1023) *ptr_n = smem[1023];
}

__global__ void scan_add4(int* __restrict__ pP, int* __restrict__ pS,
                          int* __restrict__ pO, int* __restrict__ pA,
                          const int* __restrict__ boff) {
    int i = blockIdx.x * blockDim.x + threadIdx.x;
    int* ptr; int loc; int off;
    if (i < 50000)       { ptr = pP; loc = i;          off = 0; }
    else if (i < 100000) { ptr = pS; loc = i - 50000;  off = 64; }
    else if (i < 105000) { ptr = pO; loc = i - 100000; off = 128; }
    else if (i < NTOT)   { ptr = pA; loc = i - 105000; off = 192; }
    else return;
    ptr[loc] += boff[off + (loc >> 10)];
}

// ---------------------------------------------------------------------------
// csr_body2: TWO nodes per wave, online softmax, 1-ahead prefetch
// (verified r10-20).  INIT mode: out = x+bsum+conv as a pure write.
// ---------------------------------------------------------------------------
template <bool INIT>
__device__ __forceinline__ void csr_body2(
    const unsigned short* __restrict__ xl, int ldl,
    const unsigned short* __restrict__ xr, int ldr,
    const float* __restrict__ att,
    const int* __restrict__ ptr, const int* __restrict__ srcs,
    const float* __restrict__ xbase, const float* __restrict__ b1,
    const float* __restrict__ b2,
    float* __restrict__ out, int n) {
    const int tid = threadIdx.x;
    const int node = blockIdx.x * 8 + (tid >> 5);
    if (node >= n) return;
    const int gl = tid & 31;
    const int beg = ptr[node], end = ptr[node + 1];
    if (!INIT && beg == end) return;

    constexpr int V = 8;
    const int c0 = gl * V;

    float runM = -3.0e38f, runS = 0.0f;
    float acc[V] = {};

    if (INIT || beg < end) {
        float av[V], rvf[V];
        {
            const unsigned short* pr = xr + (size_t)node * ldr + c0;
            unsigned short rv[V];
            *(uint4*)rv = *(const uint4*)pr;
#pragma unroll
            for (int v4 = 0; v4 < V / 4; ++v4)
                *(float4*)(av + v4 * 4) = ((const float4*)(att + c0))[v4];
#pragma unroll
            for (int v = 0; v < V; ++v) rvf[v] = bf2f(rv[v]);
        }

        if (beg < end) {
            unsigned short lv[V];
            {
                const unsigned short* pl = xl + (size_t)srcs[beg] * ldl + c0;
                *(uint4*)lv = *(const uint4*)pl;
            }
            for (int j = beg; j < end; ++j) {
                float cf[V];
#pragma unroll
                for (int v = 0; v < V; ++v) cf[v] = bf2f(lv[v]);
                if (j + 1 < end) {
                    const unsigned short* pl = xl + (size_t)srcs[j + 1] * ldl + c0;
                    *(uint4*)lv = *(const uint4*)pl;
                }

                float part = 0.0f;
#pragma unroll
                for (int v = 0; v < V; ++v) {
                    float m = cf[v] + rvf[v];
                    m = (m >= 0.0f) ? m : 0.2f * m;
                    part += m * av[v];
                }
                part += __shfl_xor(part, 1, 64);
                part += __shfl_xor(part, 2, 64);
                part += __shfl_xor(part, 4, 64);
                part += __shfl_xor(part, 8, 64);
                part += __shfl_xor(part, 16, 64);

                const float newM = fmaxf(runM, part);
                const float sc = __expf(runM - newM);
                const float e1 = __expf(part - newM);
                runS = runS * sc + e1;
                runM = newM;
#pragma unroll
                for (int v = 0; v < V; ++v) acc[v] = acc[v] * sc + e1 * cf[v];
            }
        }
    }

    const float inv = 1.0f / fmaxf(runS, 1e-16f);
    float* po = out + (size_t)node * 256 + c0;
    if (INIT) {
        const float* px = xbase + (size_t)node * 256 + c0;
#pragma unroll
        for (int v4 = 0; v4 < V / 4; ++v4) {
            float4 xv = ((const float4*)px)[v4];
            float4 bv1 = ((const float4*)(b1 + c0))[v4];
            float4 bv2 = ((const float4*)(b2 + c0))[v4];
            float4 o;
            o.x = xv.x + bv1.x + bv2.x + acc[v4 * 4 + 0] * inv;
            o.y = xv.y + bv1.y + bv2.y + acc[v4 * 4 + 1] * inv;
            o.z = xv.z + bv1.z + bv2.z + acc[v4 * 4 + 2] * inv;
            o.w = xv.w + bv1.w + bv2.w + acc[v4 * 4 + 3] * inv;
            ((float4*)po)[v4] = o;
        }
    } else {
#pragma unroll
        for (int v4 = 0; v4 < V / 4; ++v4) {
            float4 o = ((float4*)po)[v4];
            o.x += acc[v4 * 4 + 0] * inv;
            o.y += acc[v4 * 4 + 1] * inv;
            o.z += acc[v4 * 4 + 2] * inv;
            o.w += acc[v4 * 4 + 3] * inv;
            ((float4*)po)[v4] = o;
        }
    }
}

__global__ void csr_init2(const unsigned short* __restrict__ xl, int ldl,
                          const unsigned short* __restrict__ xr, int ldr,
                          const float* __restrict__ att,
                          const int* __restrict__ ptr, const int* __restrict__ srcs,
                          const float* __restrict__ xbase,
                          const float* __restrict__ b1, const float* __restrict__ b2,
                          float* __restrict__ out, int n) {
    csr_body2<true>(xl, ldl, xr, ldr, att, ptr, srcs, xbase, b1, b2, out, n);
}

__global__ void csr_serial2(const unsigned short* __restrict__ xl, int ldl,
                            const unsigned short* __restrict__ xr, int ldr,
                            const float* __restrict__ att,
                            const int* __restrict__ ptr, const int* __restrict__ srcs,
                            float* __restrict__ out, int n) {
    csr_body2<false>(xl, ldl, xr, ldr, att, ptr, srcs, nullptr, nullptr, nullptr, out, n);
}

// ---------------------------------------------------------------------------
// csrg_body: 16-lane-group, 4 edges in flight, now with 1-CHUNK-AHEAD
// prefetch (mirrors verified csr_serial2 pattern): the next chunk's rows
// (and ea row for EF) are loaded before the current chunk's compute, so the
// first-touch HBM miss overlaps the ~250-cycle dot/shfl/softmax chain.
// ---------------------------------------------------------------------------
template <bool EF>
__device__ __forceinline__ void csrg_body(
    const unsigned short* __restrict__ xl, const unsigned short* __restrict__ xr,
    const float* __restrict__ att,
    const int* __restrict__ ptr, const int* __restrict__ srcs,
    const int* __restrict__ eid, const float* __restrict__ ea,
    const float* __restrict__ We,
    float* __restrict__ out, int n, int blk) {
    const int node = blk * 4 + ((int)threadIdx.x >> 6);
    if (node >= n) return;
    const int lane = threadIdx.x & 63;
    const int grp  = lane >> 4;
    const int sl   = lane & 15;
    const int beg = ptr[node], end = ptr[node + 1];
    if (beg == end) return;

    constexpr int W = 8;
    const int c0 = sl * W;

    float av[W], rvf[W];
    {
        const unsigned short* pr = xr + (size_t)node * 128 + c0;
        unsigned short rv[W];
        *(uint4*)rv = *(const uint4*)pr;
#pragma unroll
        for (int v4 = 0; v4 < 2; ++v4)
            *(float4*)(av + v4 * 4) = ((const float4*)(att + c0))[v4];
#pragma unroll
        for (int v = 0; v < W; ++v) rvf[v] = bf2f(rv[v]);
    }

    float wreg[64];
    if constexpr (EF) {
#pragma unroll
        for (int k = 0; k < 8; ++k) {
            *(float4*)(wreg + k * 8)     = *(const float4*)(We + k * 128 + c0);
            *(float4*)(wreg + k * 8 + 4) = *(const float4*)(We + k * 128 + c0 + 4);
        }
    }

    float runM = -3.0e38f, runS = 0.0f;
    float acc[W] = {};

    // ---- preload chunk 0 ----
    unsigned short lv[W];
    float eav[8];
    {
        const int j0 = beg + grp;
        const int js0 = (j0 < end) ? j0 : end - 1;
        *(uint4*)lv = *(const uint4*)(xl + (size_t)srcs[js0] * 128 + c0);
        if constexpr (EF) {
            const int oe = eid[js0];
            *(float4*)eav       = *(const float4*)(ea + (size_t)oe * 8);
            *(float4*)(eav + 4) = *(const float4*)(ea + (size_t)oe * 8 + 4);
        }
    }

    for (int cb = beg; cb < end; cb += 4) {
        const int j = cb + grp;
        const bool act = (j < end);

        float cf[W];
#pragma unroll
        for (int v = 0; v < W; ++v) cf[v] = bf2f(lv[v]);
        float eavc[8];
        if constexpr (EF) {
#pragma unroll
            for (int k = 0; k < 8; ++k) eavc[k] = eav[k];
        }

        // ---- prefetch next chunk ----
        if (cb + 4 < end) {
            const int jn = cb + 4 + grp;
            const int jsn = (jn < end) ? jn : end - 1;
            *(uint4*)lv = *(const uint4*)(xl + (size_t)srcs[jsn] * 128 + c0);
            if constexpr (EF) {
                const int oe = eid[jsn];
                *(float4*)eav       = *(const float4*)(ea + (size_t)oe * 8);
                *(float4*)(eav + 4) = *(const float4*)(ea + (size_t)oe * 8 + 4);
            }
        }

        float part = 0.0f;
        if constexpr (EF) {
#pragma unroll
            for (int v = 0; v < W; ++v) {
                float efv = eavc[0] * wreg[v];
#pragma unroll
                for (int k = 1; k < 8; ++k) efv += eavc[k] * wreg[k * 8 + v];
                float m = cf[v] + rvf[v] + efv;
                m = (m >= 0.0f) ? m : 0.2f * m;
                part += m * av[v];
            }
        } else {
#pragma unroll
            for (int v = 0; v < W; ++v) {
                float m = cf[v] + rvf[v];
                m = (m >= 0.0f) ? m : 0.2f * m;
                part += m * av[v];
            }
        }
        part += __shfl_xor(part, 1, 64);
        part += __shfl_xor(part, 2, 64);
        part += __shfl_xor(part, 4, 64);
        part += __shfl_xor(part, 8, 64);
        if (!act) part = -3.0e38f;

        float cm = fmaxf(part, __shfl_xor(part, 16, 64));
        cm = fmaxf(cm, __shfl_xor(cm, 32, 64));

        if (cm > runM) {
            const float sc = __expf(runM - cm);
            runS *= sc;
#pragma unroll
            for (int v = 0; v < W; ++v) acc[v] *= sc;
            runM = cm;
        }
        const float w = act ? __expf(part - runM) : 0.0f;
        float cs = w + __shfl_xor(w, 16, 64);
        cs += __shfl_xor(cs, 32, 64);
        runS += cs;
#pragma unroll
        for (int v = 0; v < W; ++v) acc[v] += w * cf[v];
    }

#pragma unroll
    for (int v = 0; v < W; ++v) acc[v] += __shfl_xor(acc[v], 16, 64);
#pragma unroll
    for (int v = 0; v < W; ++v) acc[v] += __shfl_xor(acc[v], 32, 64);

    const float inv = 1.0f / fmaxf(runS, 1e-16f);
    if (grp == 0) {
        float* po = out + (size_t)node * 128 + c0;
#pragma unroll
        for (int v4 = 0; v4 < 2; ++v4) {
            float4 o = ((float4*)po)[v4];
            o.x += acc[v4 * 4 + 0] * inv;
            o.y += acc[v4 * 4 + 1] * inv;
            o.z += acc[v4 * 4 + 2] * inv;
            o.w += acc[v4 * 4 + 3] * inv;
            ((float4*)po)[v4] = o;
        }
    }
}

// split kernels: each compiles at its own VGPR footprint (r15 lesson)
__global__ void csr_o2m(
    const unsigned short* __restrict__ xlb, const unsigned short* __restrict__ xrb,
    const float* __restrict__ att,
    const int* __restrict__ ptr, const int* __restrict__ srcs,
    float* __restrict__ out_m) {
    csrg_body<false>(xlb, xrb, att, ptr, srcs, nullptr, nullptr, nullptr,
                     out_m, N_M, blockIdx.x);
}

__global__ void csr_m2a(
    const unsigned short* __restrict__ xlb, const unsigned short* __restrict__ xrb,
    const float* __restrict__ att,
    const int* __restrict__ ptr, const int* __restrict__ srcs,
    const int* __restrict__ eid, const float* __restrict__ ea,
    const float* __restrict__ We, float* __restrict__ out_a) {
    csrg_body<true>(xlb, xrb, att, ptr, srcs, eid, ea, We,
                    out_a, N_A, blockIdx.x);
}

// ---------------------------------------------------------------------------
// Workspace layout (float slots).  Ends 25,383,572 floats = 101.5 MB.
// ---------------------------------------------------------------------------
#define F_H      0
#define F_XCOP   12800000
#define F_XCM    19200000
#define F_XCA    19520000
#define F_BTP    19648000
#define F_BTS    19713536
#define F_BTOL   19779072
#define F_BTOR   19795456
#define F_BTML   19803648
#define F_BTMR   19811840
#define F_BIASP  19820032
#define F_BIASS  19820544
#define F_CNT4   19821056    // int[107000]
#define F_BSUM   19928056
#define F_BOFF   19928312
#define F_PTR_P  19928568
#define F_SRC_P  19978569
#define F_PTR_S  20178569
#define F_SRC_S  20228570
#define F_PTR_O  20428570
#define F_SRC_O  20433571
#define F_PTR_A  20633571
#define F_SRC_A  20635572
#define F_EID_A  20695572
#define F_RANK   20755572    // int[660000] -> 21,415,572
#define F_XLO    21415572
#define F_XRO    24615572
#define F_XLM    24935572
#define F_XRM    25255572    // ends 25,383,572

extern "C" void kernel_launch(void* const* d_in, const int* in_sizes, int n_in,
                              void* d_out, int out_size, void* d_ws, size_t ws_size,
                              hipStream_t stream) {
    const float* x_op    = (const float*)d_in[0];
    const float* x_m     = (const float*)d_in[1];
    const float* x_a     = (const float*)d_in[2];
    const int*   ei_pred = (const int*)d_in[3];
    const int*   ei_succ = (const int*)d_in[4];
    const int*   src_o2m = (const int*)d_in[5];
    const int*   dst_o2m = (const int*)d_in[6];
    const int*   src_m2a = (const int*)d_in[7];
    const int*   dst_m2a = (const int*)d_in[8];
    const float* ea_m2a  = (const float*)d_in[9];

    const float* Wl_pred = (const float*)d_in[10];
    const float* bl_pred = (const float*)d_in[11];
    const float* Wr_pred = (const float*)d_in[12];
    const float* br_pred = (const float*)d_in[13];
    const float* att_pred= (const float*)d_in[14];
    const float* b_pred  = (const float*)d_in[15];

    const float* Wl_succ = (const float*)d_in[16];
    const float* bl_succ = (const float*)d_in[17];
    const float* Wr_succ = (const float*)d_in[18];
    const float* br_succ = (const float*)d_in[19];
    const float* att_succ= (const float*)d_in[20];
    const float* b_succ  = (const float*)d_in[21];

    const float* Wl_o2m  = (const float*)d_in[22];
    const float* bl_o2m  = (const float*)d_in[23];
    const float* Wr_o2m  = (const float*)d_in[24];
    const float* br_o2m  = (const float*)d_in[25];
    const float* att_o2m = (const float*)d_in[26];
    const float* b_o2m   = (const float*)d_in[27];

    const float* Wl_m2a  = (const float*)d_in[28];
    const float* bl_m2a  = (const float*)d_in[29];
    const float* Wr_m2a  = (const float*)d_in[30];
    const float* br_m2a  = (const float*)d_in[31];
    const float* att_m2a = (const float*)d_in[32];
    const float* b_m2a   = (const float*)d_in[33];
    const float* We_m2a  = (const float*)d_in[34];

    float* ws = (float*)d_ws;
    unsigned short* H     = (unsigned short*)(ws + F_H);
    unsigned short* xc_op = (unsigned short*)(ws + F_XCOP);
    unsigned short* xc_m  = (unsigned short*)(ws + F_XCM);
    unsigned short* xc_a  = (unsigned short*)(ws + F_XCA);
    unsigned short* BtP   = (unsigned short*)(ws + F_BTP);
    unsigned short* BtS   = (unsigned short*)(ws + F_BTS);
    unsigned short* BtOL  = (unsigned short*)(ws + F_BTOL);
    unsigned short* BtOR  = (unsigned short*)(ws + F_BTOR);
    unsigned short* BtML  = (unsigned short*)(ws + F_BTML);
    unsigned short* BtMR  = (unsigned short*)(ws + F_BTMR);
    float* biasP = ws + F_BIASP;
    float* biasS = ws + F_BIASS;
    int* cntP = (int*)(ws + F_CNT4);
    int* cntS = cntP + 50000;
    int* cntO = cntP + 100000;
    int* cntA = cntP + 105000;
    int* bsum = (int*)(ws + F_BSUM);
    int* boff = (int*)(ws + F_BOFF);
    int* ptrP = (int*)(ws + F_PTR_P); int* srcP = (int*)(ws + F_SRC_P);
    int* ptrS = (int*)(ws + F_PTR_S); int* srcS = (int*)(ws + F_SRC_S);
    int* ptrO = (int*)(ws + F_PTR_O); int* srcO = (int*)(ws + F_SRC_O);
    int* ptrA = (int*)(ws + F_PTR_A); int* srcA = (int*)(ws + F_SRC_A);
    int* eidA = (int*)(ws + F_EID_A);
    int* rk   = (int*)(ws + F_RANK);
    unsigned short* xlbO = (unsigned short*)(ws + F_XLO);
    unsigned short* xrbO = (unsigned short*)(ws + F_XRO);
    unsigned short* xlbM = (unsigned short*)(ws + F_XLM);
    unsigned short* xrbM = (unsigned short*)(ws + F_XRM);

    float* out_op = (float*)d_out + OUT_OP_OFF;
    float* out_m  = (float*)d_out + OUT_M_OFF;
    float* out_a  = (float*)d_out + OUT_A_OFF;

    // 1. zero counters (DMA fill)
    hipMemsetAsync(cntP, 0, NTOT * sizeof(int), stream);

    // 2. fused prep (1-in-6 hist interleave, 4 edges/thread; op convert-only)
    prep_all<<<PREP_TOTAL, 256, 0, stream>>>(
        ei_pred + E_OO, ei_succ + E_OO, dst_o2m, dst_m2a,
        cntP, cntS, cntO, cntA, rk,
        x_op, x_m, x_a, b_o2m, b_m2a,
        out_m, out_a, xc_op, xc_m, xc_a,
        Wl_pred, Wr_pred, Wl_succ, Wr_succ, Wl_o2m, Wr_o2m, Wl_m2a, Wr_m2a,
        bl_pred, br_pred, bl_succ, br_succ,
        BtP, BtS, BtOL, BtOR, BtML, BtMR, biasP, biasS);

    // 3-5. scan chain
    scan_blk4<<<NB_P + NB_S + NB_O + NB_A, 1024, 0, stream>>>(cntP, cntS, cntO, cntA,
                                                              ptrP, ptrS, ptrO, ptrA, bsum);
    scan_tops4<<<4, 1024, 0, stream>>>(bsum, boff, ptrP, ptrS, ptrO, ptrA);
    scan_add4<<<(NTOT + 255) / 256, 256, 0, stream>>>(ptrP, ptrS, ptrO, ptrA, boff);

    // 6. conv-1 GEMM + small GEMMs + CSR scatter (A-reuse XCD-clustered)
    gemm_multi<<<GM_TOTAL, 256, 0, stream>>>(
        xc_op, xc_m, xc_a, BtP, biasP, H,
        BtOL, BtOR, BtML, BtMR, bl_o2m, br_o2m, bl_m2a, br_m2a,
        xlbO, xrbO, xlbM, xrbM,
        ei_pred, ei_pred + E_OO, ei_succ, ei_succ + E_OO,
        src_o2m, dst_o2m, src_m2a, dst_m2a,
        ptrP, ptrS, ptrO, ptrA, rk,
        srcP, srcS, srcO, srcA, eidA);

    // 7. csr-pred (INIT mode: out_op = x + b_pred + b_succ + conv, pure write)
    csr_init2<<<(N_OP + 7) / 8, 256, 0, stream>>>(H, 512, H + 256, 512,
                                                  att_pred, ptrP, srcP,
                                                  x_op, b_pred, b_succ,
                                                  out_op, N_OP);

    // 8. conv-2 GEMM (succ; XCD-clustered; overwrites H after csr-pred)
    mfma_gemm<<<MT_OPB * 4, 256, 0, stream>>>(xc_op, BtS, biasS, H, N_OP, 256, 512);

    // 9. csr-succ (RMW accumulate)
    csr_serial2<<<(N_OP + 7) / 8, 256, 0, stream>>>(H, 512, H + 256, 512,
                                                    att_succ, ptrS, srcS, out_op, N_OP);

    // 10. csr-o2m (non-EF, own VGPR class, chunk-ahead prefetch)
    csr_o2m<<<(N_M + 3) / 4, 256, 0, stream>>>(xlbO, xrbO, att_o2m,
                                               ptrO, srcO, out_m);

    // 11. csr-m2a (EF inline, chunk-ahead prefetch)
    csr_m2a<<<(N_A + 3) / 4, 256, 0, stream>>>(xlbM, xrbM, att_m2a,
                                               ptrA, srcA, eidA, ea_m2a, We_m2a, out_a);
}

// Round 22
// 251.337 us; speedup vs baseline: 1.0232x; 1.0232x over previous
//
#include <hip/hip_runtime.h>

// ---------------------------------------------------------------------------
// Problem constants (fixed by setup_inputs)
// ---------------------------------------------------------------------------
#define N_OP   50000
#define N_M    5000
#define N_A    2000
#define C_OP   256
#define C_M    128
#define C_A    128
#define E_OO   200000
#define E_OM   200000
#define E_MA   60000
#define E_DIM  8

#define OUT_OP_OFF 0
#define OUT_M_OFF  (N_OP * C_OP)
#define OUT_A_OFF  (N_OP * C_OP + N_M * C_M)

typedef short bf16x8 __attribute__((ext_vector_type(8)));
typedef float f32x4 __attribute__((ext_vector_type(4)));
typedef __attribute__((address_space(1))) const unsigned gu32;
typedef __attribute__((address_space(3))) unsigned lu32;

__device__ __forceinline__ unsigned short f2bf(float f) {
    unsigned u = __float_as_uint(f);
    unsigned r = (u + 0x7FFFu + ((u >> 16) & 1u)) >> 16;
    return (unsigned short)r;
}
__device__ __forceinline__ float bf2f(unsigned short h) {
    return __uint_as_float(((unsigned)h) << 16);
}

// ---------------------------------------------------------------------------
// Fused prep: hist+rank / convert (op) / init+convert (m,a) / weight-pack
// (verified rounds 19-20).
// ---------------------------------------------------------------------------
#define NTOT 107000
#define ETOT 660000

#define I3_OP (N_OP * C_OP / 4)
#define I3_M  (I3_OP + N_M * C_M / 4)
#define I3_A  (I3_M + N_A * C_A / 4)

#define PK_P   131072
#define PK_S   262144
#define PK_OL  294912
#define PK_OR  311296
#define PK_ML  327680
#define PK_MR  344064
#define PK_BP  344576
#define PK_BS  345088

#define PREP_HIST_BLK 645                       // ceil(660000 / 1024)
#define PREP_INIT_BLK (I3_A / 256)              // 13375
#define PREP_PACK_BLK (PK_BS / 256)             // 1348
#define PREP_FRONT    (6 * PREP_HIST_BLK)       // 3870
#define PREP_TOTAL    (PREP_HIST_BLK + PREP_INIT_BLK + PREP_PACK_BLK)

__device__ __forceinline__ void init_one(const float* __restrict__ x,
                                         const float* __restrict__ b1,
                                         float* __restrict__ out,
                                         unsigned short* __restrict__ xc,
                                         int i, int cmask) {
    float4 v = ((const float4*)x)[i];
    const int cb = i & cmask;
    float4 b = ((const float4*)b1)[cb];
    float4 o;
    o.x = v.x + b.x; o.y = v.y + b.y; o.z = v.z + b.z; o.w = v.w + b.w;
    ((float4*)out)[i] = o;
    ushort4 r;
    r.x = f2bf(v.x); r.y = f2bf(v.y); r.z = f2bf(v.z); r.w = f2bf(v.w);
    ((ushort4*)xc)[i] = r;
}

__device__ __forceinline__ void hist_one(
    int i,
    const int* __restrict__ dP, const int* __restrict__ dS,
    const int* __restrict__ dO, const int* __restrict__ dA,
    int* __restrict__ cP, int* __restrict__ cS,
    int* __restrict__ cO, int* __restrict__ cA, int* __restrict__ rk) {
    if (i < 200000)      rk[i] = atomicAdd(&cP[dP[i]], 1);
    else if (i < 400000) rk[i] = atomicAdd(&cS[dS[i - 200000]], 1);
    else if (i < 600000) rk[i] = atomicAdd(&cO[dO[i - 400000]], 1);
    else if (i < ETOT)   rk[i] = atomicAdd(&cA[dA[i - 600000]], 1);
}

__global__ void prep_all(
    const int* __restrict__ dP, const int* __restrict__ dS,
    const int* __restrict__ dO, const int* __restrict__ dA,
    int* __restrict__ cP, int* __restrict__ cS,
    int* __restrict__ cO, int* __restrict__ cA, int* __restrict__ rk,
    const float* __restrict__ x_op, const float* __restrict__ x_m,
    const float* __restrict__ x_a,
    const float* __restrict__ bO, const float* __restrict__ bA,
    float* __restrict__ out_m, float* __restrict__ out_a,
    unsigned short* __restrict__ xcop, unsigned short* __restrict__ xcm,
    unsigned short* __restrict__ xca,
    const float* __restrict__ WlP, const float* __restrict__ WrP,
    const float* __restrict__ WlS, const float* __restrict__ WrS,
    const float* __restrict__ WOl, const float* __restrict__ WOr,
    const float* __restrict__ WMl, const float* __restrict__ WMr,
    const float* __restrict__ blP, const float* __restrict__ brP,
    const float* __restrict__ blS, const float* __restrict__ brS,
    unsigned short* __restrict__ BtP, unsigned short* __restrict__ BtS,
    unsigned short* __restrict__ BtOL, unsigned short* __restrict__ BtOR,
    unsigned short* __restrict__ BtML, unsigned short* __restrict__ BtMR,
    float* __restrict__ biasP, float* __restrict__ biasS) {
    const int b = blockIdx.x;
    const int tid = threadIdx.x;
    int ib;
    if (b < PREP_FRONT) {
        if ((b % 6) == 5) {              // hist role: 4 edges per thread
            const int h = b / 6;
            const int base = h * 1024 + tid;
            hist_one(base,       dP, dS, dO, dA, cP, cS, cO, cA, rk);
            hist_one(base + 256, dP, dS, dO, dA, cP, cS, cO, cA, rk);
            hist_one(base + 512, dP, dS, dO, dA, cP, cS, cO, cA, rk);
            hist_one(base + 768, dP, dS, dO, dA, cP, cS, cO, cA, rk);
            return;
        }
        ib = b - b / 6;
    } else {
        ib = b - PREP_HIST_BLK;
    }
    if (ib < PREP_INIT_BLK) {
        int i = ib * 256 + tid;
        if (i < I3_OP) {
            float4 v = ((const float4*)x_op)[i];
            ushort4 r;
            r.x = f2bf(v.x); r.y = f2bf(v.y); r.z = f2bf(v.z); r.w = f2bf(v.w);
            ((ushort4*)xcop)[i] = r;
        } else if (i < I3_M) {
            init_one(x_m, bO, out_m, xcm, i - I3_OP, 31);
        } else {
            init_one(x_a, bA, out_a, xca, i - I3_M, 31);
        }
    } else {
        int i = (ib - PREP_INIT_BLK) * 256 + tid;
        if (i < PK_P) {
            int n = i >> 8, k = i & 255;
            BtP[i] = f2bf((n < 256) ? WlP[k * 256 + n] : WrP[k * 256 + (n - 256)]);
        } else if (i < PK_S) {
            int j = i - PK_P; int n = j >> 8, k = j & 255;
            BtS[j] = f2bf((n < 256) ? WlS[k * 256 + n] : WrS[k * 256 + (n - 256)]);
        } else if (i < PK_OL) {
            int j = i - PK_S; int n = j >> 8, k = j & 255;
            BtOL[j] = f2bf(WOl[k * 128 + n]);
        } else if (i < PK_OR) {
            int j = i - PK_OL; int n = j >> 7, k = j & 127;
            BtOR[j] = f2bf(WOr[k * 128 + n]);
        } else if (i < PK_ML) {
            int j = i - PK_OR; int n = j >> 7, k = j & 127;
            BtML[j] = f2bf(WMl[k * 128 + n]);
        } else if (i < PK_MR) {
            int j = i - PK_ML; int n = j >> 7, k = j & 127;
            BtMR[j] = f2bf(WMr[k * 128 + n]);
        } else if (i < PK_BP) {
            int j = i - PK_MR;
            biasP[j] = (j < 256) ? blP[j] : brP[j - 256];
        } else if (i < PK_BS) {
            int j = i - PK_BP;
            biasS[j] = (j < 256) ? blS[j] : brS[j - 256];
        }
    }
}

// ---------------------------------------------------------------------------
// MFMA bf16 GEMM body: m97 structure — 128x128 tile, BK=64, single-buffered
// 32KB LDS, XOR-swizzled (verified rounds 15-20).
// ---------------------------------------------------------------------------
__device__ __forceinline__ void gload_lds16(const void* g, void* l) {
    __builtin_amdgcn_global_load_lds((gu32*)g, (lu32*)l, 16, 0, 0);
}

__device__ __forceinline__ void gemm_body(
    const unsigned short* __restrict__ A, const unsigned short* __restrict__ Bt,
    const float* __restrict__ bias, unsigned short* __restrict__ C,
    int M, int K, int ldc, int bx, int by,
    unsigned short (&As)[128 * 64], unsigned short (&Bs)[128 * 64]) {
    const int tid  = threadIdx.x;
    const int lane = tid & 63;
    const int wid  = tid >> 6;
    const int m0   = bx * 128;
    const int n0   = by * 128;

    f32x4 acc[4][4] = {};

    const int srow   = tid >> 3;
    const int scolb  = (tid & 7) * 16;
    const int scole  = (scolb ^ ((srow & 7) << 4)) >> 1;

    int grA[4], grB[4];
#pragma unroll
    for (int i = 0; i < 4; ++i) {
        int gr = m0 + i * 32 + srow;
        grA[i] = (gr < M) ? gr : M - 1;
        grB[i] = n0 + i * 32 + srow;
    }

    const int nt = K >> 6;
    const int wr = (wid >> 1) * 64;
    const int wc = (wid & 1) * 64;

    for (int t = 0; t < nt; ++t) {
#pragma unroll
        for (int i = 0; i < 4; ++i)
            gload_lds16(A + (size_t)grA[i] * K + t * 64 + scole, &As[i * 2048 + tid * 8]);
#pragma unroll
        for (int i = 0; i < 4; ++i)
            gload_lds16(Bt + (size_t)grB[i] * K + t * 64 + scole, &Bs[i * 2048 + tid * 8]);
        asm volatile("s_waitcnt vmcnt(0)" ::: "memory");
        __syncthreads();
#pragma unroll
        for (int kh = 0; kh < 2; ++kh) {
            const int kob = kh * 64 + (lane >> 4) * 16;
            bf16x8 a[4], b[4];
#pragma unroll
            for (int mi = 0; mi < 4; ++mi) {
                const int row = wr + mi * 16 + (lane & 15);
                a[mi] = *(const bf16x8*)((const char*)As + row * 128 +
                                         (kob ^ ((row & 7) << 4)));
            }
#pragma unroll
            for (int ni = 0; ni < 4; ++ni) {
                const int row = wc + ni * 16 + (lane & 15);
                b[ni] = *(const bf16x8*)((const char*)Bs + row * 128 +
                                         (kob ^ ((row & 7) << 4)));
            }
#pragma unroll
            for (int mi = 0; mi < 4; ++mi)
#pragma unroll
                for (int ni = 0; ni < 4; ++ni)
                    acc[mi][ni] = __builtin_amdgcn_mfma_f32_16x16x32_bf16(
                        a[mi], b[ni], acc[mi][ni], 0, 0, 0);
        }
        __syncthreads();
    }

    const int crow = (lane >> 4) * 4;
    const int ccol = lane & 15;
    float bcol[4];
#pragma unroll
    for (int ni = 0; ni < 4; ++ni) bcol[ni] = bias[n0 + wc + ni * 16 + ccol];
#pragma unroll
    for (int mi = 0; mi < 4; ++mi) {
#pragma unroll
        for (int j = 0; j < 4; ++j) {
            const int row = m0 + wr + mi * 16 + crow + j;
            if (row < M) {
                unsigned short* pc = C + (size_t)row * ldc + n0 + wc + ccol;
#pragma unroll
                for (int ni = 0; ni < 4; ++ni)
                    pc[ni * 16] = f2bf(acc[mi][ni][j] + bcol[ni]);
            }
        }
    }
}

// succ GEMM with bijective XCD-chunk swizzle (verified rounds 17-20)
__global__ __launch_bounds__(256) void mfma_gemm(
    const unsigned short* __restrict__ A, const unsigned short* __restrict__ Bt,
    const float* __restrict__ bias, unsigned short* __restrict__ C,
    int M, int K, int ldc) {
    __shared__ unsigned short As[128 * 64];
    __shared__ unsigned short Bs[128 * 64];
    const int b = blockIdx.x;
    const int xcd = b & 7, pos = b >> 3;
    const int lb = ((xcd < 4) ? xcd * 196 : 4 * 196 + (xcd - 4) * 195) + pos;
    gemm_body(A, Bt, bias, C, M, K, ldc, lb >> 2, lb & 3, As, Bs);
}

// ---------------------------------------------------------------------------
// gemm_multi: conv-1 GEMM + o2m-L 5-per-A-tile XCD-clustered + 3 tiny GEMMs
// + atomic-free CSR scatter (verified rounds 17-20).
// ---------------------------------------------------------------------------
#define MT_OPB 391
#define MT_MB  40
#define MT_AB  16
#define GM_SWZ   1955
#define GM_SMALL 2051
#define GM_TOTAL 4630

__global__ __launch_bounds__(256) void gemm_multi(
    const unsigned short* __restrict__ xc_op, const unsigned short* __restrict__ xc_m,
    const unsigned short* __restrict__ xc_a,
    const unsigned short* __restrict__ BtP, const float* __restrict__ biasP,
    unsigned short* __restrict__ H,
    const unsigned short* __restrict__ BtOL, const unsigned short* __restrict__ BtOR,
    const unsigned short* __restrict__ BtML, const unsigned short* __restrict__ BtMR,
    const float* __restrict__ blO, const float* __restrict__ brO,
    const float* __restrict__ blM, const float* __restrict__ brM,
    unsigned short* __restrict__ xlbO, unsigned short* __restrict__ xrbO,
    unsigned short* __restrict__ xlbM, unsigned short* __restrict__ xrbM,
    const int* __restrict__ sP, const int* __restrict__ dP,
    const int* __restrict__ sS, const int* __restrict__ dS,
    const int* __restrict__ sO, const int* __restrict__ dO,
    const int* __restrict__ sA, const int* __restrict__ dA,
    const int* __restrict__ pP, const int* __restrict__ pS,
    const int* __restrict__ pO, const int* __restrict__ pA,
    const int* __restrict__ rk,
    int* __restrict__ srP, int* __restrict__ srS,
    int* __restrict__ srO, int* __restrict__ srA, int* __restrict__ eiA) {
    __shared__ unsigned short As[128 * 64];
    __shared__ unsigned short Bs[128 * 64];
    const int b = blockIdx.x;
    if (b < GM_SWZ) {
        const int xcd = b & 7, pos = b >> 3;
        const int lb = ((xcd < 3) ? xcd * 245 : 3 * 245 + (xcd - 3) * 244) + pos;
        const int bx = lb / 5, role = lb - bx * 5;
        if (role < 4)
            gemm_body(xc_op, BtP, biasP, H, N_OP, 256, 512, bx, role, As, Bs);
        else
            gemm_body(xc_op, BtOL, blO, xlbO, N_OP, 256, 128, bx, 0, As, Bs);
    } else if (b < GM_SMALL) {
        const int idx = b - GM_SWZ;
        if (idx < MT_MB)
            gemm_body(xc_m, BtOR, brO, xrbO, N_M, 128, 128, idx, 0, As, Bs);
        else if (idx < 2 * MT_MB)
            gemm_body(xc_m, BtML, blM, xlbM, N_M, 128, 128, idx - MT_MB, 0, As, Bs);
        else
            gemm_body(xc_a, BtMR, brM, xrbM, N_A, 128, 128, idx - 2 * MT_MB, 0, As, Bs);
    } else {
        const int i = (b - GM_SMALL) * 256 + (int)threadIdx.x;
        if (i < 200000) {
            srP[pP[dP[i]] + rk[i]] = sP[i];
        } else if (i < 400000) {
            const int j = i - 200000;
            srS[pS[dS[j]] + rk[i]] = sS[j];
        } else if (i < 600000) {
            const int j = i - 400000;
            srO[pO[dO[j]] + rk[i]] = sO[j];
        } else if (i < ETOT) {
            const int j = i - 600000;
            const int pos = pA[dA[j]] + rk[i];
            srA[pos] = sA[j];
            eiA[pos] = j;
        }
    }
}

// ---------------------------------------------------------------------------
// CSR scan chain (verified r4-20)
// ---------------------------------------------------------------------------
#define NB_P 49
#define NB_S 49
#define NB_O 5
#define NB_A 2

__global__ void scan_blk4(const int* __restrict__ cP, const int* __restrict__ cS,
                          const int* __restrict__ cO, const int* __restrict__ cA,
                          int* __restrict__ pP, int* __restrict__ pS,
                          int* __restrict__ pO, int* __restrict__ pA,
                          int* __restrict__ bsum) {
    __shared__ int smem[1024];
    int b = blockIdx.x;
    const int* cnt; int* ptr; int n; int bo;
    if (b < NB_P)                { cnt = cP; ptr = pP; n = 50000; bo = 0; }
    else if (b < NB_P + NB_S)    { cnt = cS; ptr = pS; n = 50000; bo = 64;  b -= NB_P; }
    else if (b < NB_P + NB_S + NB_O) { cnt = cO; ptr = pO; n = 5000; bo = 128; b -= NB_P + NB_S; }
    else                         { cnt = cA; ptr = pA; n = 2000; bo = 192; b -= NB_P + NB_S + NB_O; }
    const int tid = threadIdx.x;
    const int i = b * 1024 + tid;
    const int v = (i < n) ? cnt[i] : 0;
    smem[tid] = v;
    __syncthreads();
    for (int o = 1; o < 1024; o <<= 1) {
        int t = (tid >= o) ? smem[tid - o] : 0;
        __syncthreads();
        smem[tid] += t;
        __syncthreads();
    }
    if (i < n) ptr[i] = smem[tid] - v;
    if (tid == 1023) bsum[bo + b] = smem[1023];
}

__global__ void scan_tops4(const int* __restrict__ bsum, int* __restrict__ boff,
                           int* __restrict__ pP, int* __restrict__ pS,
                           int* __restrict__ pO, int* __restrict__ pA) {
    __shared__ int smem[1024];
    const int seg = blockIdx.x;
    const int nb = (seg < 2) ? 49 : (seg == 2 ? 5 : 2);
    const int off = seg * 64;
    int* ptr_n = (seg == 0) ? pP + 50000 : (seg == 1) ? pS + 50000
               : (seg == 2) ? pO + 5000 : pA + 2000;
    const int tid = threadIdx.x;
    const int v = (tid < nb) ? bsum[off + tid] : 0;
    smem[tid] = v;
    __syncthreads();
    for (int o = 1; o < 1024; o <<= 1) {
        int t = (tid >= o) ? smem[tid - o] : 0;
        __syncthreads();
        smem[tid] += t;
        __syncthreads();
    }
    if (tid < nb) boff[off + tid] = smem[tid] - v;
    if (tid == 1023) *ptr_n = smem[1023];
}

__global__ void scan_add4(int* __restrict__ pP, int* __restrict__ pS,
                          int* __restrict__ pO, int* __restrict__ pA,
                          const int* __restrict__ boff) {
    int i = blockIdx.x * blockDim.x + threadIdx.x;
    int* ptr; int loc; int off;
    if (i < 50000)       { ptr = pP; loc = i;          off = 0; }
    else if (i < 100000) { ptr = pS; loc = i - 50000;  off = 64; }
    else if (i < 105000) { ptr = pO; loc = i - 100000; off = 128; }
    else if (i < NTOT)   { ptr = pA; loc = i - 105000; off = 192; }
    else return;
    ptr[loc] += boff[off + (loc >> 10)];
}

// ---------------------------------------------------------------------------
// csr_body2: TWO nodes per wave, online softmax, 1-ahead prefetch
// (verified r10-20).  INIT mode: out = x+bsum+conv as a pure write.
// ---------------------------------------------------------------------------
template <bool INIT>
__device__ __forceinline__ void csr_body2(
    const unsigned short* __restrict__ xl, int ldl,
    const unsigned short* __restrict__ xr, int ldr,
    const float* __restrict__ att,
    const int* __restrict__ ptr, const int* __restrict__ srcs,
    const float* __restrict__ xbase, const float* __restrict__ b1,
    const float* __restrict__ b2,
    float* __restrict__ out, int n) {
    const int tid = threadIdx.x;
    const int node = blockIdx.x * 8 + (tid >> 5);
    if (node >= n) return;
    const int gl = tid & 31;
    const int beg = ptr[node], end = ptr[node + 1];
    if (!INIT && beg == end) return;

    constexpr int V = 8;
    const int c0 = gl * V;

    float runM = -3.0e38f, runS = 0.0f;
    float acc[V] = {};

    if (INIT || beg < end) {
        float av[V], rvf[V];
        {
            const unsigned short* pr = xr + (size_t)node * ldr + c0;
            unsigned short rv[V];
            *(uint4*)rv = *(const uint4*)pr;
#pragma unroll
            for (int v4 = 0; v4 < V / 4; ++v4)
                *(float4*)(av + v4 * 4) = ((const float4*)(att + c0))[v4];
#pragma unroll
            for (int v = 0; v < V; ++v) rvf[v] = bf2f(rv[v]);
        }

        if (beg < end) {
            unsigned short lv[V];
            {
                const unsigned short* pl = xl + (size_t)srcs[beg] * ldl + c0;
                *(uint4*)lv = *(const uint4*)pl;
            }
            for (int j = beg; j < end; ++j) {
                float cf[V];
#pragma unroll
                for (int v = 0; v < V; ++v) cf[v] = bf2f(lv[v]);
                if (j + 1 < end) {
                    const unsigned short* pl = xl + (size_t)srcs[j + 1] * ldl + c0;
                    *(uint4*)lv = *(const uint4*)pl;
                }

                float part = 0.0f;
#pragma unroll
                for (int v = 0; v < V; ++v) {
                    float m = cf[v] + rvf[v];
                    m = (m >= 0.0f) ? m : 0.2f * m;
                    part += m * av[v];
                }
                part += __shfl_xor(part, 1, 64);
                part += __shfl_xor(part, 2, 64);
                part += __shfl_xor(part, 4, 64);
                part += __shfl_xor(part, 8, 64);
                part += __shfl_xor(part, 16, 64);

                const float newM = fmaxf(runM, part);
                const float sc = __expf(runM - newM);
                const float e1 = __expf(part - newM);
                runS = runS * sc + e1;
                runM = newM;
#pragma unroll
                for (int v = 0; v < V; ++v) acc[v] = acc[v] * sc + e1 * cf[v];
            }
        }
    }

    const float inv = 1.0f / fmaxf(runS, 1e-16f);
    float* po = out + (size_t)node * 256 + c0;
    if (INIT) {
        const float* px = xbase + (size_t)node * 256 + c0;
#pragma unroll
        for (int v4 = 0; v4 < V / 4; ++v4) {
            float4 xv = ((const float4*)px)[v4];
            float4 bv1 = ((const float4*)(b1 + c0))[v4];
            float4 bv2 = ((const float4*)(b2 + c0))[v4];
            float4 o;
            o.x = xv.x + bv1.x + bv2.x + acc[v4 * 4 + 0] * inv;
            o.y = xv.y + bv1.y + bv2.y + acc[v4 * 4 + 1] * inv;
            o.z = xv.z + bv1.z + bv2.z + acc[v4 * 4 + 2] * inv;
            o.w = xv.w + bv1.w + bv2.w + acc[v4 * 4 + 3] * inv;
            ((float4*)po)[v4] = o;
        }
    } else {
#pragma unroll
        for (int v4 = 0; v4 < V / 4; ++v4) {
            float4 o = ((float4*)po)[v4];
            o.x += acc[v4 * 4 + 0] * inv;
            o.y += acc[v4 * 4 + 1] * inv;
            o.z += acc[v4 * 4 + 2] * inv;
            o.w += acc[v4 * 4 + 3] * inv;
            ((float4*)po)[v4] = o;
        }
    }
}

__global__ void csr_init2(const unsigned short* __restrict__ xl, int ldl,
                          const unsigned short* __restrict__ xr, int ldr,
                          const float* __restrict__ att,
                          const int* __restrict__ ptr, const int* __restrict__ srcs,
                          const float* __restrict__ xbase,
                          const float* __restrict__ b1, const float* __restrict__ b2,
                          float* __restrict__ out, int n) {
    csr_body2<true>(xl, ldl, xr, ldr, att, ptr, srcs, xbase, b1, b2, out, n);
}

__global__ void csr_serial2(const unsigned short* __restrict__ xl, int ldl,
                            const unsigned short* __restrict__ xr, int ldr,
                            const float* __restrict__ att,
                            const int* __restrict__ ptr, const int* __restrict__ srcs,
                            float* __restrict__ out, int n) {
    csr_body2<false>(xl, ldl, xr, ldr, att, ptr, srcs, nullptr, nullptr, nullptr, out, n);
}

// ---------------------------------------------------------------------------
// csrg_body: 16-lane-group, 4 edges in flight (verified r8-20), C=128.
// EF variant computes edge features inline (We in 64 regs).
// ---------------------------------------------------------------------------
template <bool EF>
__device__ __forceinline__ void csrg_body(
    const unsigned short* __restrict__ xl, const unsigned short* __restrict__ xr,
    const float* __restrict__ att,
    const int* __restrict__ ptr, const int* __restrict__ srcs,
    const int* __restrict__ eid, const float* __restrict__ ea,
    const float* __restrict__ We,
    float* __restrict__ out, int n, int blk) {
    const int node = blk * 4 + ((int)threadIdx.x >> 6);
    if (node >= n) return;
    const int lane = threadIdx.x & 63;
    const int grp  = lane >> 4;
    const int sl   = lane & 15;
    const int beg = ptr[node], end = ptr[node + 1];
    if (beg == end) return;

    constexpr int W = 8;
    const int c0 = sl * W;

    float av[W], rvf[W];
    {
        const unsigned short* pr = xr + (size_t)node * 128 + c0;
        unsigned short rv[W];
        *(uint4*)rv = *(const uint4*)pr;
#pragma unroll
        for (int v4 = 0; v4 < 2; ++v4)
            *(float4*)(av + v4 * 4) = ((const float4*)(att + c0))[v4];
#pragma unroll
        for (int v = 0; v < W; ++v) rvf[v] = bf2f(rv[v]);
    }

    float wreg[64];
    if constexpr (EF) {
#pragma unroll
        for (int k = 0; k < 8; ++k) {
            *(float4*)(wreg + k * 8)     = *(const float4*)(We + k * 128 + c0);
            *(float4*)(wreg + k * 8 + 4) = *(const float4*)(We + k * 128 + c0 + 4);
        }
    }

    float runM = -3.0e38f, runS = 0.0f;
    float acc[W] = {};

    for (int cb = beg; cb < end; cb += 4) {
        const int j = cb + grp;
        const bool act = (j < end);
        const int js = act ? j : end - 1;
        const int s = srcs[js];

        const unsigned short* pl = xl + (size_t)s * 128 + c0;
        unsigned short lv[W];
        *(uint4*)lv = *(const uint4*)pl;
        float cf[W];
#pragma unroll
        for (int v = 0; v < W; ++v) cf[v] = bf2f(lv[v]);

        float part = 0.0f;
        if constexpr (EF) {
            const int oe = eid[js];
            float eav[8];
            *(float4*)eav       = *(const float4*)(ea + (size_t)oe * 8);
            *(float4*)(eav + 4) = *(const float4*)(ea + (size_t)oe * 8 + 4);
#pragma unroll
            for (int v = 0; v < W; ++v) {
                float efv = eav[0] * wreg[v];
#pragma unroll
                for (int k = 1; k < 8; ++k) efv += eav[k] * wreg[k * 8 + v];
                float m = cf[v] + rvf[v] + efv;
                m = (m >= 0.0f) ? m : 0.2f * m;
                part += m * av[v];
            }
        } else {
#pragma unroll
            for (int v = 0; v < W; ++v) {
                float m = cf[v] + rvf[v];
                m = (m >= 0.0f) ? m : 0.2f * m;
                part += m * av[v];
            }
        }
        part += __shfl_xor(part, 1, 64);
        part += __shfl_xor(part, 2, 64);
        part += __shfl_xor(part, 4, 64);
        part += __shfl_xor(part, 8, 64);
        if (!act) part = -3.0e38f;

        float cm = fmaxf(part, __shfl_xor(part, 16, 64));
        cm = fmaxf(cm, __shfl_xor(cm, 32, 64));

        if (cm > runM) {
            const float sc = __expf(runM - cm);
            runS *= sc;
#pragma unroll
            for (int v = 0; v < W; ++v) acc[v] *= sc;
            runM = cm;
        }
        const float w = act ? __expf(part - runM) : 0.0f;
        float cs = w + __shfl_xor(w, 16, 64);
        cs += __shfl_xor(cs, 32, 64);
        runS += cs;
#pragma unroll
        for (int v = 0; v < W; ++v) acc[v] += w * cf[v];
    }

#pragma unroll
    for (int v = 0; v < W; ++v) acc[v] += __shfl_xor(acc[v], 16, 64);
#pragma unroll
    for (int v = 0; v < W; ++v) acc[v] += __shfl_xor(acc[v], 32, 64);

    const float inv = 1.0f / fmaxf(runS, 1e-16f);
    if (grp == 0) {
        float* po = out + (size_t)node * 128 + c0;
#pragma unroll
        for (int v4 = 0; v4 < 2; ++v4) {
            float4 o = ((float4*)po)[v4];
            o.x += acc[v4 * 4 + 0] * inv;
            o.y += acc[v4 * 4 + 1] * inv;
            o.z += acc[v4 * 4 + 2] * inv;
            o.w += acc[v4 * 4 + 3] * inv;
            ((float4*)po)[v4] = o;
        }
    }
}

// csr-o2m + csr-m2a (LDS-free, same csrg VGPR class; verified r13-20)
#define CP_O 1250
__global__ void csr_pair(
    const unsigned short* __restrict__ xlbO, const unsigned short* __restrict__ xrbO,
    const float* __restrict__ attO,
    const int* __restrict__ ptrO, const int* __restrict__ srcO,
    float* __restrict__ out_m,
    const unsigned short* __restrict__ xlbM, const unsigned short* __restrict__ xrbM,
    const float* __restrict__ attA,
    const int* __restrict__ ptrA, const int* __restrict__ srcA,
    const int* __restrict__ eidA, const float* __restrict__ ea,
    const float* __restrict__ We, float* __restrict__ out_a) {
    const int b = blockIdx.x;
    if (b < CP_O)
        csrg_body<false>(xlbO, xrbO, attO, ptrO, srcO, nullptr, nullptr, nullptr,
                         out_m, N_M, b);
    else
        csrg_body<true>(xlbM, xrbM, attA, ptrA, srcA, eidA, ea, We,
                        out_a, N_A, b - CP_O);
}

// ---------------------------------------------------------------------------
// Workspace layout (float slots).  Ends 25,383,572 floats = 101.5 MB.
// ---------------------------------------------------------------------------
#define F_H      0
#define F_XCOP   12800000
#define F_XCM    19200000
#define F_XCA    19520000
#define F_BTP    19648000
#define F_BTS    19713536
#define F_BTOL   19779072
#define F_BTOR   19795456
#define F_BTML   19803648
#define F_BTMR   19811840
#define F_BIASP  19820032
#define F_BIASS  19820544
#define F_CNT4   19821056    // int[107000]
#define F_BSUM   19928056
#define F_BOFF   19928312
#define F_PTR_P  19928568
#define F_SRC_P  19978569
#define F_PTR_S  20178569
#define F_SRC_S  20228570
#define F_PTR_O  20428570
#define F_SRC_O  20433571
#define F_PTR_A  20633571
#define F_SRC_A  20635572
#define F_EID_A  20695572
#define F_RANK   20755572    // int[660000] -> 21,415,572
#define F_XLO    21415572
#define F_XRO    24615572
#define F_XLM    24935572
#define F_XRM    25255572    // ends 25,383,572

extern "C" void kernel_launch(void* const* d_in, const int* in_sizes, int n_in,
                              void* d_out, int out_size, void* d_ws, size_t ws_size,
                              hipStream_t stream) {
    const float* x_op    = (const float*)d_in[0];
    const float* x_m     = (const float*)d_in[1];
    const float* x_a     = (const float*)d_in[2];
    const int*   ei_pred = (const int*)d_in[3];
    const int*   ei_succ = (const int*)d_in[4];
    const int*   src_o2m = (const int*)d_in[5];
    const int*   dst_o2m = (const int*)d_in[6];
    const int*   src_m2a = (const int*)d_in[7];
    const int*   dst_m2a = (const int*)d_in[8];
    const float* ea_m2a  = (const float*)d_in[9];

    const float* Wl_pred = (const float*)d_in[10];
    const float* bl_pred = (const float*)d_in[11];
    const float* Wr_pred = (const float*)d_in[12];
    const float* br_pred = (const float*)d_in[13];
    const float* att_pred= (const float*)d_in[14];
    const float* b_pred  = (const float*)d_in[15];

    const float* Wl_succ = (const float*)d_in[16];
    const float* bl_succ = (const float*)d_in[17];
    const float* Wr_succ = (const float*)d_in[18];
    const float* br_succ = (const float*)d_in[19];
    const float* att_succ= (const float*)d_in[20];
    const float* b_succ  = (const float*)d_in[21];

    const float* Wl_o2m  = (const float*)d_in[22];
    const float* bl_o2m  = (const float*)d_in[23];
    const float* Wr_o2m  = (const float*)d_in[24];
    const float* br_o2m  = (const float*)d_in[25];
    const float* att_o2m = (const float*)d_in[26];
    const float* b_o2m   = (const float*)d_in[27];

    const float* Wl_m2a  = (const float*)d_in[28];
    const float* bl_m2a  = (const float*)d_in[29];
    const float* Wr_m2a  = (const float*)d_in[30];
    const float* br_m2a  = (const float*)d_in[31];
    const float* att_m2a = (const float*)d_in[32];
    const float* b_m2a   = (const float*)d_in[33];
    const float* We_m2a  = (const float*)d_in[34];

    float* ws = (float*)d_ws;
    unsigned short* H     = (unsigned short*)(ws + F_H);
    unsigned short* xc_op = (unsigned short*)(ws + F_XCOP);
    unsigned short* xc_m  = (unsigned short*)(ws + F_XCM);
    unsigned short* xc_a  = (unsigned short*)(ws + F_XCA);
    unsigned short* BtP   = (unsigned short*)(ws + F_BTP);
    unsigned short* BtS   = (unsigned short*)(ws + F_BTS);
    unsigned short* BtOL  = (unsigned short*)(ws + F_BTOL);
    unsigned short* BtOR  = (unsigned short*)(ws + F_BTOR);
    unsigned short* BtML  = (unsigned short*)(ws + F_BTML);
    unsigned short* BtMR  = (unsigned short*)(ws + F_BTMR);
    float* biasP = ws + F_BIASP;
    float* biasS = ws + F_BIASS;
    int* cntP = (int*)(ws + F_CNT4);
    int* cntS = cntP + 50000;
    int* cntO = cntP + 100000;
    int* cntA = cntP + 105000;
    int* bsum = (int*)(ws + F_BSUM);
    int* boff = (int*)(ws + F_BOFF);
    int* ptrP = (int*)(ws + F_PTR_P); int* srcP = (int*)(ws + F_SRC_P);
    int* ptrS = (int*)(ws + F_PTR_S); int* srcS = (int*)(ws + F_SRC_S);
    int* ptrO = (int*)(ws + F_PTR_O); int* srcO = (int*)(ws + F_SRC_O);
    int* ptrA = (int*)(ws + F_PTR_A); int* srcA = (int*)(ws + F_SRC_A);
    int* eidA = (int*)(ws + F_EID_A);
    int* rk   = (int*)(ws + F_RANK);
    unsigned short* xlbO = (unsigned short*)(ws + F_XLO);
    unsigned short* xrbO = (unsigned short*)(ws + F_XRO);
    unsigned short* xlbM = (unsigned short*)(ws + F_XLM);
    unsigned short* xrbM = (unsigned short*)(ws + F_XRM);

    float* out_op = (float*)d_out + OUT_OP_OFF;
    float* out_m  = (float*)d_out + OUT_M_OFF;
    float* out_a  = (float*)d_out + OUT_A_OFF;

    // 1. zero counters (DMA fill)
    hipMemsetAsync(cntP, 0, NTOT * sizeof(int), stream);

    // 2. fused prep (1-in-6 hist interleave, 4 edges/thread; op convert-only)
    prep_all<<<PREP_TOTAL, 256, 0, stream>>>(
        ei_pred + E_OO, ei_succ + E_OO, dst_o2m, dst_m2a,
        cntP, cntS, cntO, cntA, rk,
        x_op, x_m, x_a, b_o2m, b_m2a,
        out_m, out_a, xc_op, xc_m, xc_a,
        Wl_pred, Wr_pred, Wl_succ, Wr_succ, Wl_o2m, Wr_o2m, Wl_m2a, Wr_m2a,
        bl_pred, br_pred, bl_succ, br_succ,
        BtP, BtS, BtOL, BtOR, BtML, BtMR, biasP, biasS);

    // 3-5. scan chain
    scan_blk4<<<NB_P + NB_S + NB_O + NB_A, 1024, 0, stream>>>(cntP, cntS, cntO, cntA,
                                                              ptrP, ptrS, ptrO, ptrA, bsum);
    scan_tops4<<<4, 1024, 0, stream>>>(bsum, boff, ptrP, ptrS, ptrO, ptrA);
    scan_add4<<<(NTOT + 255) / 256, 256, 0, stream>>>(ptrP, ptrS, ptrO, ptrA, boff);

    // 6. conv-1 GEMM + small GEMMs + CSR scatter (A-reuse XCD-clustered)
    gemm_multi<<<GM_TOTAL, 256, 0, stream>>>(
        xc_op, xc_m, xc_a, BtP, biasP, H,
        BtOL, BtOR, BtML, BtMR, bl_o2m, br_o2m, bl_m2a, br_m2a,
        xlbO, xrbO, xlbM, xrbM,
        ei_pred, ei_pred + E_OO, ei_succ, ei_succ + E_OO,
        src_o2m, dst_o2m, src_m2a, dst_m2a,
        ptrP, ptrS, ptrO, ptrA, rk,
        srcP, srcS, srcO, srcA, eidA);

    // 7. csr-pred (INIT mode: out_op = x + b_pred + b_succ + conv, pure write)
    csr_init2<<<(N_OP + 7) / 8, 256, 0, stream>>>(H, 512, H + 256, 512,
                                                  att_pred, ptrP, srcP,
                                                  x_op, b_pred, b_succ,
                                                  out_op, N_OP);

    // 8. conv-2 GEMM (succ; XCD-clustered; overwrites H after csr-pred)
    mfma_gemm<<<MT_OPB * 4, 256, 0, stream>>>(xc_op, BtS, biasS, H, N_OP, 256, 512);

    // 9. csr-succ (RMW accumulate)
    csr_serial2<<<(N_OP + 7) / 8, 256, 0, stream>>>(H, 512, H + 256, 512,
                                                    att_succ, ptrS, srcS, out_op, N_OP);

    // 10. csr-o2m + csr-m2a (inline edge features)
    csr_pair<<<CP_O + (N_A + 3) / 4, 256, 0, stream>>>(
        xlbO, xrbO, att_o2m, ptrO, srcO, out_m,
        xlbM, xrbM, att_m2a, ptrA, srcA, eidA, ea_m2a, We_m2a, out_a);
}